// Round 16
// baseline (225.507 us; speedup 1.0000x reference)
//
#include <hip/hip_runtime.h>

// ============ MEASUREMENT BUILD: internal amplification ============
// Per-kernel true cost = reported dur / AMP. Correctness unchanged
// (amplified iterations recompute identical values; outputs idempotent).
#define BBOX_AMP     6
#define STRIPE_AMP   8
#define FINISH_AMP   14
// ===================================================================

#define NUM_NETS     100000
#define PINS_PER_NET 5
#define NUM_PINS     (NUM_NETS * PINS_PER_NET)
#define NB           512
#define BIN_H        1.953125f          /* 1000/512, exact in fp32 */
#define INV_H        0.512f             /* 512/1000 */
#define OUT_SCALE    (1.0f / 195.3125f) /* 1/(BIN_SIZE_X * 100 tracks) */

#define SW           8                  /* stripe width (x bins) */
#define NSTRIPES     (NB / SW)          /* 64 */
#define CAP          24576              /* items per stripe bucket (worst ~16K) */

#define FXS          2097152.0f         /* 2^21 fixed-point scale */
#define INV_FXS      (1.0f / 2097152.0f)

// ---------------------------------------------------------------------------
// K_0: zero the 64 stripe cursors.
// ---------------------------------------------------------------------------
__global__ void zero_kernel(int* __restrict__ gcur) {
    gcur[threadIdx.x] = 0;
}

// ---------------------------------------------------------------------------
// K_A: bbox + emit. Gather/bbox phase amplified x BBOX_AMP.
// ---------------------------------------------------------------------------
__global__ __launch_bounds__(256) void bbox_emit_kernel(
        const float* __restrict__ pin_pos,
        const int*   __restrict__ flat_netpin,
        const float* __restrict__ net_weights,
        int* __restrict__ gcur,
        float4* __restrict__ bucket) {
    __shared__ int lcnt[NSTRIPES];
    __shared__ int lbase[NSTRIPES];
    int tid = threadIdx.x;
    if (tid < NSTRIPES) lcnt[tid] = 0;
    __syncthreads();

    int n = blockIdx.x * 256 + tid;
    bool valid = n < NUM_NETS;
    float xmn = 1e30f, xmx = -1e30f, ymn = 1e30f, ymx = -1e30f;
    float wh = 0.f, wv = 0.f;
    int kx1 = 0, kx2 = 0;
    if (valid) {
#pragma unroll 1
        for (int it = 0; it < BBOX_AMP; ++it) {
            xmn = 1e30f; xmx = -1e30f; ymn = 1e30f; ymx = -1e30f;
#pragma unroll
            for (int p = 0; p < PINS_PER_NET; ++p) {
                int pi  = flat_netpin[n * PINS_PER_NET + p];
                float x = pin_pos[pi];
                float y = pin_pos[NUM_PINS + pi];
                xmn = fminf(xmn, x); xmx = fmaxf(xmx, x);
                ymn = fminf(ymn, y); ymx = fmaxf(ymx, y);
            }
            float w = net_weights[n];
            wh = w / (ymx - ymn);
            wv = w / (xmx - xmn);
            kx1 = min(NB - 1, (int)(xmn * INV_H));
            kx2 = min(NB - 1, (int)(xmx * INV_H));
            asm volatile("" ::: "memory");   /* force reload next iter */
        }
#pragma unroll
        for (int cx = 0; cx < 2; ++cx) {
            int kx = cx ? kx2 : kx1;
            int s0 = kx >> 3;
            atomicAdd(&lcnt[s0], 2);
            if (kx + 1 < NB && ((kx + 1) >> 3) != s0)
                atomicAdd(&lcnt[(kx + 1) >> 3], 2);
        }
    }
    __syncthreads();
    if (tid < NSTRIPES) {
        lbase[tid] = atomicAdd(&gcur[tid], lcnt[tid]);
        lcnt[tid] = 0;
    }
    __syncthreads();
    if (valid) {
#pragma unroll
        for (int cx = 0; cx < 2; ++cx) {
            int   kx = cx ? kx2 : kx1;
            float xc = cx ? xmx : xmn;
            int s0 = kx >> 3;
            int s1 = (kx + 1 < NB) ? ((kx + 1) >> 3) : s0;
#pragma unroll
            for (int cy = 0; cy < 2; ++cy) {
                float yc = cy ? ymx : ymn;
                float sg = ((cx ^ cy) ? -1.0f : 1.0f);
                float4 item = make_float4(xc, yc, sg * wh, sg * wv);
                {
                    int rank = atomicAdd(&lcnt[s0], 1);
                    int pos  = lbase[s0] + rank;
                    if (pos < CAP) bucket[(size_t)s0 * CAP + pos] = item;
                }
                if (s1 != s0) {
                    int rank = atomicAdd(&lcnt[s1], 1);
                    int pos  = lbase[s1] + rank;
                    if (pos < CAP) bucket[(size_t)s1 * CAP + pos] = item;
                }
            }
        }
    }
}

// ---------------------------------------------------------------------------
// K_B: stripe kernel, full body amplified x STRIPE_AMP (idempotent).
// ---------------------------------------------------------------------------
__global__ __launch_bounds__(1024) void stripe_kernel(
        const float4* __restrict__ bucket,
        const int* __restrict__ gcur,
        float* __restrict__ UpH, float* __restrict__ UpV,
        float* __restrict__ Th,  float* __restrict__ Tv) {
    __shared__ int   acc[2 * SW * NB];          /* 32 KB: H then V */
    __shared__ float wsc[32];
    int st  = blockIdx.x;
    int tid = threadIdx.x;
    int x0  = st * SW;
    int* accH = acc;
    int* accV = acc + SW * NB;

#pragma unroll 1
    for (int it = 0; it < STRIPE_AMP; ++it) {
        for (int k = tid; k < 2 * SW * NB; k += 1024) acc[k] = 0;
        __syncthreads();

        /* ---- accumulate (int fixed-point, native LDS atomics) ---- */
        int cnt = min(gcur[st], CAP);
        const float4* bk = bucket + (size_t)st * CAP;
        for (int q = tid; q < cnt; q += 1024) {
            float4 it4 = bk[q];
            int kx = min(NB - 1, (int)(it4.x * INV_H));
            int ky = min(NB - 1, (int)(it4.y * INV_H));
            float dx0 = (kx + 1) * BIN_H - it4.x;
            float dx1 = it4.x - kx * BIN_H;
            float dy0 = (ky + 1) * BIN_H - it4.y;
            float dy1 = it4.y - ky * BIN_H;
            bool y1ok = (ky + 1) < NB;
            int c = kx - x0;
#pragma unroll
            for (int cc = 0; cc < 2; ++cc) {
                int col = c + cc;
                if ((unsigned)col < SW) {
                    float dx = cc ? dx1 : dx0;
                    int b = col * NB + ky;
                    atomicAdd(&accH[b], __float2int_rn(it4.z * dx * dy0 * FXS));
                    atomicAdd(&accV[b], __float2int_rn(it4.w * dx * dy0 * FXS));
                    if (y1ok) {
                        atomicAdd(&accH[b + 1], __float2int_rn(it4.z * dx * dy1 * FXS));
                        atomicAdd(&accV[b + 1], __float2int_rn(it4.w * dx * dy1 * FXS));
                    }
                }
            }
        }
        __syncthreads();

        /* ---- convert int -> float in place ---- */
        float* fH = (float*)accH;
        float* fV = (float*)accV;
        for (int k = tid; k < 2 * SW * NB; k += 1024)
            ((float*)acc)[k] = (float)acc[k] * INV_FXS;
        __syncthreads();

        /* ---- y-scan: 8 rows x 512, two rows per pass ---- */
        int half = tid >> 9;
        int y    = tid & 511;
        int lane = tid & 63;
        int wv16 = tid >> 6;
        int wrow0 = half * 8;
#pragma unroll
        for (int rp = 0; rp < 4; ++rp) {
            int row = rp * 2 + half;
            float vH = fH[row * NB + y];
            float vV = fV[row * NB + y];
#pragma unroll
            for (int o = 1; o < 64; o <<= 1) {
                float a = __shfl_up(vH, o);
                float b = __shfl_up(vV, o);
                if (lane >= o) { vH += a; vV += b; }
            }
            if (lane == 63) { wsc[wv16] = vH; wsc[16 + wv16] = vV; }
            __syncthreads();
            float oh = 0.f, ov = 0.f;
            for (int j = wrow0; j < wv16; ++j) { oh += wsc[j]; ov += wsc[16 + j]; }
            fH[row * NB + y] = vH + oh;
            fV[row * NB + y] = vV + ov;
            __syncthreads();
        }

        /* ---- x-partial scan over the 8 rows + totals ---- */
        if (tid < NB) {
            float f = 0.f;
#pragma unroll
            for (int rr = 0; rr < SW; ++rr) {
                int i = rr * NB + tid;
                f += fH[i]; fH[i] = f;
            }
            Th[st * NB + tid] = f;
        } else {
            int yy = tid - NB;
            float f = 0.f;
#pragma unroll
            for (int rr = 0; rr < SW; ++rr) {
                int i = rr * NB + yy;
                f += fV[i]; fV[i] = f;
            }
            Tv[st * NB + yy] = f;
        }
        __syncthreads();

        /* ---- dump scanned partials ---- */
        for (int k = tid; k < SW * NB; k += 1024) {
            int rr = k >> 9, yy = k & (NB - 1);
            int gi = (x0 + rr) * NB + yy;
            UpH[gi] = fH[k];
            UpV[gi] = fV[k];
        }
        __syncthreads();   /* before next iteration re-zeroes LDS */
    }
}

// ---------------------------------------------------------------------------
// K_C: finish, amplified x FINISH_AMP (idempotent).
// ---------------------------------------------------------------------------
__global__ __launch_bounds__(512) void finish_kernel(
        const float* __restrict__ UpH, const float* __restrict__ UpV,
        const float* __restrict__ Th,  const float* __restrict__ Tv,
        float* __restrict__ out) {
    int st = blockIdx.x;
    int y  = threadIdx.x;
#pragma unroll 1
    for (int it = 0; it < FINISH_AMP; ++it) {
        float offh = 0.f, offv = 0.f;
        for (int s2 = 0; s2 < st; ++s2) {
            offh += Th[s2 * NB + y];
            offv += Tv[s2 * NB + y];
        }
#pragma unroll
        for (int rr = 0; rr < SW; ++rr) {
            int i = (st * SW + rr) * NB + y;
            float h = fabsf(UpH[i] + offh) * OUT_SCALE;
            float v = fabsf(UpV[i] + offv) * OUT_SCALE;
            float m = fmaxf(h, v);
            out[i] = fminf(fmaxf(m * m, 0.5f), 2.0f);
        }
        asm volatile("" ::: "memory");   /* force reload next iter */
    }
}

// ---------------------------------------------------------------------------
// Fallback (tiny workspace): global-atomic scatter + scans
// ---------------------------------------------------------------------------
__global__ void scatter_kernel(const float* __restrict__ pin_pos,
                               const int*   __restrict__ flat_netpin,
                               const float* __restrict__ net_weights,
                               float* __restrict__ Uh,
                               float* __restrict__ Uv) {
    int n = blockIdx.x * blockDim.x + threadIdx.x;
    if (n >= NUM_NETS) return;
    float xmn = 1e30f, xmx = -1e30f, ymn = 1e30f, ymx = -1e30f;
#pragma unroll
    for (int p = 0; p < PINS_PER_NET; ++p) {
        int pi  = flat_netpin[n * PINS_PER_NET + p];
        float x = pin_pos[pi];
        float y = pin_pos[NUM_PINS + pi];
        xmn = fminf(xmn, x); xmx = fmaxf(xmx, x);
        ymn = fminf(ymn, y); ymx = fmaxf(ymx, y);
    }
    float w  = net_weights[n];
    float wh = w / (ymx - ymn), wv = w / (xmx - xmn);
    int kx1 = min(NB - 1, (int)(xmn * INV_H));
    int kx2 = min(NB - 1, (int)(xmx * INV_H));
    int ky1 = min(NB - 1, (int)(ymn * INV_H));
    int ky2 = min(NB - 1, (int)(ymx * INV_H));
    int   xi[4] = { kx1, kx1 + 1, kx2, kx2 + 1 };
    float xv[4] = { (kx1 + 1) * BIN_H - xmn,  xmn - kx1 * BIN_H,
                    xmx - (kx2 + 1) * BIN_H,  kx2 * BIN_H - xmx };
    int   yi[4] = { ky1, ky1 + 1, ky2, ky2 + 1 };
    float yv[4] = { (ky1 + 1) * BIN_H - ymn,  ymn - ky1 * BIN_H,
                    ymx - (ky2 + 1) * BIN_H,  ky2 * BIN_H - ymx };
#pragma unroll
    for (int a = 0; a < 4; ++a) {
        if (xi[a] >= NB) continue;
#pragma unroll
        for (int b2 = 0; b2 < 4; ++b2) {
            if (yi[b2] >= NB) continue;
            float prod = xv[a] * yv[b2];
            atomicAdd(&Uh[xi[a] * NB + yi[b2]], wh * prod);
            atomicAdd(&Uv[xi[a] * NB + yi[b2]], wv * prod);
        }
    }
}

__global__ void fb_rowscan_kernel(float* __restrict__ Uh, float* __restrict__ Uv) {
    __shared__ float sh[NB];
    __shared__ float sv[NB];
    int rr = blockIdx.x, t = threadIdx.x;
    sh[t] = Uh[rr * NB + t];
    sv[t] = Uv[rr * NB + t];
    __syncthreads();
#pragma unroll
    for (int off = 1; off < NB; off <<= 1) {
        float a = (t >= off) ? sh[t - off] : 0.0f;
        float b = (t >= off) ? sv[t - off] : 0.0f;
        __syncthreads();
        sh[t] += a; sv[t] += b;
        __syncthreads();
    }
    Uh[rr * NB + t] = sh[t];
    Uv[rr * NB + t] = sv[t];
}

__global__ void fb_colscan_kernel(const float* __restrict__ Uh,
                                  const float* __restrict__ Uv,
                                  float* __restrict__ out) {
    int t = blockIdx.x * blockDim.x + threadIdx.x;
    if (t >= NB) return;
    float sh = 0.f, sv = 0.f;
    for (int i = 0; i < NB; ++i) {
        sh += Uh[i * NB + t];
        sv += Uv[i * NB + t];
        float h = fabsf(sh) * OUT_SCALE;
        float v = fabsf(sv) * OUT_SCALE;
        float m = fmaxf(h, v);
        out[i * NB + t] = fminf(fmaxf(m * m, 0.5f), 2.0f);
    }
}

extern "C" void kernel_launch(void* const* d_in, const int* in_sizes, int n_in,
                              void* d_out, int out_size, void* d_ws, size_t ws_size,
                              hipStream_t stream) {
    const float* pin_pos     = (const float*)d_in[0];
    const int*   flat_netpin = (const int*)d_in[2];
    const float* net_weights = (const float*)d_in[3];
    float* out = (float*)d_out;
    float* ws  = (float*)d_ws;

    const size_t o_cur = 0;
    const size_t o_bkt = 64;
    const size_t o_Th  = o_bkt + (size_t)NSTRIPES * CAP * 4;
    const size_t o_Tv  = o_Th + (size_t)NSTRIPES * NB;
    const size_t o_UpH = o_Tv + (size_t)NSTRIPES * NB;
    const size_t o_UpV = o_UpH + (size_t)NB * NB;
    const size_t need  = o_UpV + (size_t)NB * NB;

    if (ws_size < need * sizeof(float)) {
        float* Uh = ws;
        float* Uv = ws + (size_t)NB * NB;
        hipMemsetAsync(ws, 0, 2 * (size_t)NB * NB * sizeof(float), stream);
        scatter_kernel<<<(NUM_NETS + 255) / 256, 256, 0, stream>>>(
            pin_pos, flat_netpin, net_weights, Uh, Uv);
        fb_rowscan_kernel<<<NB, NB, 0, stream>>>(Uh, Uv);
        fb_colscan_kernel<<<2, 256, 0, stream>>>(Uh, Uv, out);
        return;
    }

    int*    gcur   = (int*)(ws + o_cur);
    float4* bucket = (float4*)(ws + o_bkt);
    float*  Th     = ws + o_Th;
    float*  Tv     = ws + o_Tv;
    float*  UpH    = ws + o_UpH;
    float*  UpV    = ws + o_UpV;

    zero_kernel<<<1, NSTRIPES, 0, stream>>>(gcur);

    bbox_emit_kernel<<<(NUM_NETS + 255) / 256, 256, 0, stream>>>(
        pin_pos, flat_netpin, net_weights, gcur, bucket);

    stripe_kernel<<<NSTRIPES, 1024, 0, stream>>>(bucket, gcur, UpH, UpV, Th, Tv);

    finish_kernel<<<NSTRIPES, 512, 0, stream>>>(UpH, UpV, Th, Tv, out);
}

// Round 17
// 50.558 us; speedup vs baseline: 4.4604x; 4.4604x over previous
//
#include <hip/hip_runtime.h>

#define NUM_NETS     100000
#define PINS_PER_NET 5
#define NUM_PINS     (NUM_NETS * PINS_PER_NET)
#define NB           512
#define BIN_H        1.953125f          /* 1000/512, exact in fp32 */
#define INV_H        0.512f             /* 512/1000 */
#define OUT_SCALE    (1.0f / 195.3125f) /* 1/(BIN_SIZE_X * 100 tracks) */

#define SW           8                  /* stripe width (x bins) */
#define NSTRIPES     (NB / SW)          /* 64 */
#define CAP          24576              /* items per stripe bucket (worst ~16K) */

#define FXS          2097152.0f         /* 2^21 fixed-point scale */
#define INV_FXS      (1.0f / 2097152.0f)

// ---------------------------------------------------------------------------
// K_0: zero the 64 stripe cursors + 64 lookback flags (each replay).
// ---------------------------------------------------------------------------
__global__ void zero_kernel(int* __restrict__ gcur) {
    gcur[threadIdx.x] = 0;              /* 128 threads: gcur[64] + flag[64] */
}

// ---------------------------------------------------------------------------
// K_A: bbox + emit 16B items {x, y, s*wh, s*wv} into per-stripe buckets.
// (unchanged from R13)
// ---------------------------------------------------------------------------
__global__ __launch_bounds__(256) void bbox_emit_kernel(
        const float* __restrict__ pin_pos,
        const int*   __restrict__ flat_netpin,
        const float* __restrict__ net_weights,
        int* __restrict__ gcur,
        float4* __restrict__ bucket) {
    __shared__ int lcnt[NSTRIPES];
    __shared__ int lbase[NSTRIPES];
    int tid = threadIdx.x;
    if (tid < NSTRIPES) lcnt[tid] = 0;
    __syncthreads();

    int n = blockIdx.x * 256 + tid;
    bool valid = n < NUM_NETS;
    float xmn = 1e30f, xmx = -1e30f, ymn = 1e30f, ymx = -1e30f;
    float wh = 0.f, wv = 0.f;
    int kx1 = 0, kx2 = 0;
    if (valid) {
#pragma unroll
        for (int p = 0; p < PINS_PER_NET; ++p) {
            int pi  = flat_netpin[n * PINS_PER_NET + p];
            float x = pin_pos[pi];
            float y = pin_pos[NUM_PINS + pi];
            xmn = fminf(xmn, x); xmx = fmaxf(xmx, x);
            ymn = fminf(ymn, y); ymx = fmaxf(ymx, y);
        }
        float w = net_weights[n];
        wh = w / (ymx - ymn);
        wv = w / (xmx - xmn);
        kx1 = min(NB - 1, (int)(xmn * INV_H));
        kx2 = min(NB - 1, (int)(xmx * INV_H));
#pragma unroll
        for (int cx = 0; cx < 2; ++cx) {
            int kx = cx ? kx2 : kx1;
            int s0 = kx >> 3;
            atomicAdd(&lcnt[s0], 2);
            if (kx + 1 < NB && ((kx + 1) >> 3) != s0)
                atomicAdd(&lcnt[(kx + 1) >> 3], 2);
        }
    }
    __syncthreads();
    if (tid < NSTRIPES) {
        lbase[tid] = atomicAdd(&gcur[tid], lcnt[tid]);
        lcnt[tid] = 0;
    }
    __syncthreads();
    if (valid) {
#pragma unroll
        for (int cx = 0; cx < 2; ++cx) {
            int   kx = cx ? kx2 : kx1;
            float xc = cx ? xmx : xmn;
            int s0 = kx >> 3;
            int s1 = (kx + 1 < NB) ? ((kx + 1) >> 3) : s0;
#pragma unroll
            for (int cy = 0; cy < 2; ++cy) {
                float yc = cy ? ymx : ymn;
                float sg = ((cx ^ cy) ? -1.0f : 1.0f);
                float4 item = make_float4(xc, yc, sg * wh, sg * wv);
                {
                    int rank = atomicAdd(&lcnt[s0], 1);
                    int pos  = lbase[s0] + rank;
                    if (pos < CAP) bucket[(size_t)s0 * CAP + pos] = item;
                }
                if (s1 != s0) {
                    int rank = atomicAdd(&lcnt[s1], 1);
                    int pos  = lbase[s1] + rank;
                    if (pos < CAP) bucket[(size_t)s1 * CAP + pos] = item;
                }
            }
        }
    }
}

// ---------------------------------------------------------------------------
// K_B: merged stripe + finish with decoupled lookback.
// Per stripe block: int-atomic accumulate -> y-scan (converting int->float
// on load) -> x-partial scan + totals -> publish totals (agent-scope atomics
// + release flag) -> lookback over s2<st -> write out directly from LDS.
// ---------------------------------------------------------------------------
__global__ __launch_bounds__(1024) void stripe_finish_kernel(
        const float4* __restrict__ bucket,
        const int* __restrict__ gcur,
        float* __restrict__ Th,  float* __restrict__ Tv,
        int* __restrict__ flag,
        float* __restrict__ out) {
    __shared__ int   acc[2 * SW * NB];          /* 32 KB: H then V */
    __shared__ float wsc[32];
    __shared__ float offHs[2][NB];              /* 4 KB */
    __shared__ float offVs[2][NB];              /* 4 KB */
    int st  = blockIdx.x;
    int tid = threadIdx.x;
    int x0  = st * SW;
    int* accH = acc;
    int* accV = acc + SW * NB;
    float* fH = (float*)accH;
    float* fV = (float*)accV;

    for (int k = tid; k < 2 * SW * NB; k += 1024) acc[k] = 0;
    __syncthreads();

    /* ---- accumulate (int fixed-point, native LDS atomics) ---- */
    int cnt = min(gcur[st], CAP);
    const float4* bk = bucket + (size_t)st * CAP;
    for (int q = tid; q < cnt; q += 1024) {
        float4 it = bk[q];
        int kx = min(NB - 1, (int)(it.x * INV_H));
        int ky = min(NB - 1, (int)(it.y * INV_H));
        float dx0 = (kx + 1) * BIN_H - it.x;
        float dx1 = it.x - kx * BIN_H;
        float dy0 = (ky + 1) * BIN_H - it.y;
        float dy1 = it.y - ky * BIN_H;
        bool y1ok = (ky + 1) < NB;
        int c = kx - x0;
#pragma unroll
        for (int cc = 0; cc < 2; ++cc) {
            int col = c + cc;
            if ((unsigned)col < SW) {
                float dx = cc ? dx1 : dx0;
                int b = col * NB + ky;
                atomicAdd(&accH[b], __float2int_rn(it.z * dx * dy0 * FXS));
                atomicAdd(&accV[b], __float2int_rn(it.w * dx * dy0 * FXS));
                if (y1ok) {
                    atomicAdd(&accH[b + 1], __float2int_rn(it.z * dx * dy1 * FXS));
                    atomicAdd(&accV[b + 1], __float2int_rn(it.w * dx * dy1 * FXS));
                }
            }
        }
    }
    __syncthreads();

    /* ---- y-scan (int->float fold on load): 8 rows x 512, 2 rows/pass ---- */
    int half = tid >> 9;
    int y    = tid & 511;
    int lane = tid & 63;
    int wv16 = tid >> 6;
    int wrow0 = half * 8;
#pragma unroll
    for (int rp = 0; rp < 4; ++rp) {
        int row = rp * 2 + half;
        float vH = (float)accH[row * NB + y] * INV_FXS;
        float vV = (float)accV[row * NB + y] * INV_FXS;
#pragma unroll
        for (int o = 1; o < 64; o <<= 1) {
            float a = __shfl_up(vH, o);
            float b = __shfl_up(vV, o);
            if (lane >= o) { vH += a; vV += b; }
        }
        if (lane == 63) { wsc[wv16] = vH; wsc[16 + wv16] = vV; }
        __syncthreads();
        float oh = 0.f, ov = 0.f;
        for (int j = wrow0; j < wv16; ++j) { oh += wsc[j]; ov += wsc[16 + j]; }
        fH[row * NB + y] = vH + oh;
        fV[row * NB + y] = vV + ov;
        __syncthreads();
    }

    /* ---- x-partial scan over the 8 rows + publish totals ---- */
    if (tid < NB) {
        float f = 0.f;
#pragma unroll
        for (int rr = 0; rr < SW; ++rr) {
            int i = rr * NB + tid;
            f += fH[i]; fH[i] = f;
        }
        __hip_atomic_store(&Th[st * NB + tid], f, __ATOMIC_RELAXED,
                           __HIP_MEMORY_SCOPE_AGENT);
    } else {
        int yy = tid - NB;
        float f = 0.f;
#pragma unroll
        for (int rr = 0; rr < SW; ++rr) {
            int i = rr * NB + yy;
            f += fV[i]; fV[i] = f;
        }
        __hip_atomic_store(&Tv[st * NB + yy], f, __ATOMIC_RELAXED,
                           __HIP_MEMORY_SCOPE_AGENT);
    }
    __syncthreads();
    if (tid == 0) {
        __threadfence();
        __hip_atomic_store(&flag[st], 1, __ATOMIC_RELEASE,
                           __HIP_MEMORY_SCOPE_AGENT);
    }

    /* ---- lookback: wait for s2 < st, then parallel offset sums ---- */
    if (tid < st) {
        while (__hip_atomic_load(&flag[tid], __ATOMIC_ACQUIRE,
                                 __HIP_MEMORY_SCOPE_AGENT) == 0) { }
    }
    __syncthreads();
    {
        float sh = 0.f, sv = 0.f;
        for (int s2 = half; s2 < st; s2 += 2) {
            sh += __hip_atomic_load(&Th[s2 * NB + y], __ATOMIC_RELAXED,
                                    __HIP_MEMORY_SCOPE_AGENT);
            sv += __hip_atomic_load(&Tv[s2 * NB + y], __ATOMIC_RELAXED,
                                    __HIP_MEMORY_SCOPE_AGENT);
        }
        offHs[half][y] = sh;
        offVs[half][y] = sv;
    }
    __syncthreads();

    /* ---- fused epilogue straight from LDS ---- */
    {
        float offh = offHs[0][y] + offHs[1][y];
        float offv = offVs[0][y] + offVs[1][y];
#pragma unroll
        for (int r2 = 0; r2 < 4; ++r2) {
            int rr = half * 4 + r2;
            float h = fabsf(fH[rr * NB + y] + offh) * OUT_SCALE;
            float v = fabsf(fV[rr * NB + y] + offv) * OUT_SCALE;
            float m = fmaxf(h, v);
            out[(x0 + rr) * NB + y] = fminf(fmaxf(m * m, 0.5f), 2.0f);
        }
    }
}

// ---------------------------------------------------------------------------
// Fallback (tiny workspace): global-atomic scatter + scans
// ---------------------------------------------------------------------------
__global__ void scatter_kernel(const float* __restrict__ pin_pos,
                               const int*   __restrict__ flat_netpin,
                               const float* __restrict__ net_weights,
                               float* __restrict__ Uh,
                               float* __restrict__ Uv) {
    int n = blockIdx.x * blockDim.x + threadIdx.x;
    if (n >= NUM_NETS) return;
    float xmn = 1e30f, xmx = -1e30f, ymn = 1e30f, ymx = -1e30f;
#pragma unroll
    for (int p = 0; p < PINS_PER_NET; ++p) {
        int pi  = flat_netpin[n * PINS_PER_NET + p];
        float x = pin_pos[pi];
        float y = pin_pos[NUM_PINS + pi];
        xmn = fminf(xmn, x); xmx = fmaxf(xmx, x);
        ymn = fminf(ymn, y); ymx = fmaxf(ymx, y);
    }
    float w  = net_weights[n];
    float wh = w / (ymx - ymn), wv = w / (xmx - xmn);
    int kx1 = min(NB - 1, (int)(xmn * INV_H));
    int kx2 = min(NB - 1, (int)(xmx * INV_H));
    int ky1 = min(NB - 1, (int)(ymn * INV_H));
    int ky2 = min(NB - 1, (int)(ymx * INV_H));
    int   xi[4] = { kx1, kx1 + 1, kx2, kx2 + 1 };
    float xv[4] = { (kx1 + 1) * BIN_H - xmn,  xmn - kx1 * BIN_H,
                    xmx - (kx2 + 1) * BIN_H,  kx2 * BIN_H - xmx };
    int   yi[4] = { ky1, ky1 + 1, ky2, ky2 + 1 };
    float yv[4] = { (ky1 + 1) * BIN_H - ymn,  ymn - ky1 * BIN_H,
                    ymx - (ky2 + 1) * BIN_H,  ky2 * BIN_H - ymx };
#pragma unroll
    for (int a = 0; a < 4; ++a) {
        if (xi[a] >= NB) continue;
#pragma unroll
        for (int b2 = 0; b2 < 4; ++b2) {
            if (yi[b2] >= NB) continue;
            float prod = xv[a] * yv[b2];
            atomicAdd(&Uh[xi[a] * NB + yi[b2]], wh * prod);
            atomicAdd(&Uv[xi[a] * NB + yi[b2]], wv * prod);
        }
    }
}

__global__ void fb_rowscan_kernel(float* __restrict__ Uh, float* __restrict__ Uv) {
    __shared__ float sh[NB];
    __shared__ float sv[NB];
    int rr = blockIdx.x, t = threadIdx.x;
    sh[t] = Uh[rr * NB + t];
    sv[t] = Uv[rr * NB + t];
    __syncthreads();
#pragma unroll
    for (int off = 1; off < NB; off <<= 1) {
        float a = (t >= off) ? sh[t - off] : 0.0f;
        float b = (t >= off) ? sv[t - off] : 0.0f;
        __syncthreads();
        sh[t] += a; sv[t] += b;
        __syncthreads();
    }
    Uh[rr * NB + t] = sh[t];
    Uv[rr * NB + t] = sv[t];
}

__global__ void fb_colscan_kernel(const float* __restrict__ Uh,
                                  const float* __restrict__ Uv,
                                  float* __restrict__ out) {
    int t = blockIdx.x * blockDim.x + threadIdx.x;
    if (t >= NB) return;
    float sh = 0.f, sv = 0.f;
    for (int i = 0; i < NB; ++i) {
        sh += Uh[i * NB + t];
        sv += Uv[i * NB + t];
        float h = fabsf(sh) * OUT_SCALE;
        float v = fabsf(sv) * OUT_SCALE;
        float m = fmaxf(h, v);
        out[i * NB + t] = fminf(fmaxf(m * m, 0.5f), 2.0f);
    }
}

extern "C" void kernel_launch(void* const* d_in, const int* in_sizes, int n_in,
                              void* d_out, int out_size, void* d_ws, size_t ws_size,
                              hipStream_t stream) {
    const float* pin_pos     = (const float*)d_in[0];
    const int*   flat_netpin = (const int*)d_in[2];
    const float* net_weights = (const float*)d_in[3];
    float* out = (float*)d_out;
    float* ws  = (float*)d_ws;

    /* layout (floats): gcur[64] | flag[64] | bucket[64*CAP*4]
                        | Th[64*512] | Tv[64*512]                 (~25.5 MB) */
    const size_t o_cur = 0;
    const size_t o_flg = 64;
    const size_t o_bkt = 128;                              /* 16B aligned */
    const size_t o_Th  = o_bkt + (size_t)NSTRIPES * CAP * 4;
    const size_t o_Tv  = o_Th + (size_t)NSTRIPES * NB;
    const size_t need  = o_Tv + (size_t)NSTRIPES * NB;

    if (ws_size < need * sizeof(float)) {
        float* Uh = ws;
        float* Uv = ws + (size_t)NB * NB;
        hipMemsetAsync(ws, 0, 2 * (size_t)NB * NB * sizeof(float), stream);
        scatter_kernel<<<(NUM_NETS + 255) / 256, 256, 0, stream>>>(
            pin_pos, flat_netpin, net_weights, Uh, Uv);
        fb_rowscan_kernel<<<NB, NB, 0, stream>>>(Uh, Uv);
        fb_colscan_kernel<<<2, 256, 0, stream>>>(Uh, Uv, out);
        return;
    }

    int*    gcur   = (int*)(ws + o_cur);
    int*    flg    = (int*)(ws + o_flg);
    float4* bucket = (float4*)(ws + o_bkt);
    float*  Th     = ws + o_Th;
    float*  Tv     = ws + o_Tv;

    zero_kernel<<<1, 128, 0, stream>>>(gcur);   /* zeroes gcur + flag */

    bbox_emit_kernel<<<(NUM_NETS + 255) / 256, 256, 0, stream>>>(
        pin_pos, flat_netpin, net_weights, gcur, bucket);

    stripe_finish_kernel<<<NSTRIPES, 1024, 0, stream>>>(
        bucket, gcur, Th, Tv, flg, out);
}